// Round 3
// baseline (329.093 us; speedup 1.0000x reference)
//
#include <hip/hip_runtime.h>

#define VNUM 6890
#define SLEN 20670      // V*3
#define NJ 24
#define NJR 19
#define NB 10
#define NROWS 219       // 1 (vt) + 10 (shapedirs) + 207 (posedirs) + 1 (ones)
#define NCOLS 480       // 456 (j*24+i, jr*w) + 24 (J_regressor)
#define RL 1440         // NCOLS*3
#define CCX_ELEMS (NROWS * RL)   // 315360 floats = 1.26 MB
#define KSPLIT 32
#define NCHUNK 216      // ceil(6890/32)

__constant__ int c_PAR[24]  = {0,0,0,0,1,2,3,4,5,6,7,8,9,9,9,12,13,14,16,17,18,19,20,21};
__constant__ int c_LOFF[10] = {0,1,4,7,10,15,18,20,22,24};

// ---------------------------------------------------------------------------
// Kernel P: CCX[r][col*3+c] = sum_v coef[v,col] * s_r[3v+c]
// Grid: 7 row-tiles(32) x 8 col-tiles(64) x 32 K-splits = 1792 blocks.
// Per thread: 2 rows x 4 cols x 3 c = 24 accs.
// NOTE round-2 bug: col tile ct=7 spans cols 448..511 > NCOLS=480. BOTH the
// G-staging and the write-out MUST guard colg < NCOLS (OOB Jreg reads +
// out-of-tile stores into row r+1 otherwise).
// ---------------------------------------------------------------------------
template <bool ATOMIC>
__global__ __launch_bounds__(256) void smpl_pre(
    const float* __restrict__ vt,
    const float* __restrict__ sd,
    const float* __restrict__ pd,
    const float* __restrict__ Jreg,
    const float* __restrict__ jr,
    const float* __restrict__ w,
    float* __restrict__ dst)
{
    __shared__ float sP[3][32][36];   // [c][row_local][v_local pad36]
    __shared__ float Gl[32][68];      // [v_local][col_local pad68]

    const int bid = blockIdx.x;
    const int ks = bid & 31;
    const int ct = (bid >> 5) & 7;
    const int rt = bid >> 8;           // 0..6
    const int r0 = rt * 32;
    const int c0 = ct * 64;
    const int t  = threadIdx.x;
    const int tc = t & 15;             // -> 4 cols (4*tc..4*tc+3)
    const int tr = t >> 4;             // -> 2 rows (2*tr, 2*tr+1)

    float acc[24];
    #pragma unroll
    for (int u = 0; u < 24; ++u) acc[u] = 0.f;

    const int ch0 = ks * 7;
    int ch1 = ch0 + 7; if (ch1 > NCHUNK) ch1 = NCHUNK;

    for (int ch = ch0; ch < ch1; ++ch) {
        const int v0 = ch * 32;
        __syncthreads();               // protect previous iteration's reads

        // ---- stage s rows: 32 rows x 48 float2, de-interleave 3v+c -> [c][r][v] ----
        #pragma unroll
        for (int it = 0; it < 6; ++it) {
            const int idx = t + it * 256;          // 0..1535
            const int rl = idx / 48;
            const int h  = idx - rl * 48;
            const int r  = r0 + rl;
            const int epos = 2 * h;                // 0..94
            const int e = 3 * v0 + epos;
            float f0 = 0.f, f1 = 0.f;
            if (r < NROWS && e < SLEN) {
                if (r == 218) { f0 = 1.f; f1 = 1.f; }
                else {
                    const float* src = (r == 0) ? vt
                                     : (r <= 10 ? sd + (size_t)(r - 1) * SLEN
                                                : pd + (size_t)(r - 11) * SLEN);
                    float2 v2 = *reinterpret_cast<const float2*>(src + e);
                    f0 = v2.x; f1 = v2.y;
                }
            }
            const int va = epos / 3,       ca = epos - va * 3;
            const int vb = (epos + 1) / 3, cb = (epos + 1) - vb * 3;
            sP[ca][rl][va] = f0;
            sP[cb][rl][vb] = f1;
        }

        // ---- stage coef tile G: 32 v x 64 cols (GUARD colg < NCOLS!) ----
        #pragma unroll
        for (int it = 0; it < 8; ++it) {
            const int g = t + it * 256;
            const int vL = g >> 6, colL = g & 63;
            const int colg = c0 + colL;
            const int vg = v0 + vL;
            float val = 0.f;
            if (vg < VNUM && colg < NCOLS) {
                if (colg < 456) {
                    const int j = colg / 24;
                    const int i = colg - j * 24;
                    val = jr[vg * NJR + j] * w[vg * NJ + i];
                } else {
                    val = Jreg[vg * NJ + (colg - 456)];
                }
            }
            Gl[vL][colL] = val;
        }
        __syncthreads();

        // ---- accumulate: 8 groups of 4 v's; 10 ds_read_b128 + 96 FMA each ----
        #pragma unroll
        for (int vq = 0; vq < 8; ++vq) {
            const int vb = 4 * vq;
            const float4 s0a = *reinterpret_cast<const float4*>(&sP[0][2 * tr][vb]);
            const float4 s1a = *reinterpret_cast<const float4*>(&sP[1][2 * tr][vb]);
            const float4 s2a = *reinterpret_cast<const float4*>(&sP[2][2 * tr][vb]);
            const float4 s0b = *reinterpret_cast<const float4*>(&sP[0][2 * tr + 1][vb]);
            const float4 s1b = *reinterpret_cast<const float4*>(&sP[1][2 * tr + 1][vb]);
            const float4 s2b = *reinterpret_cast<const float4*>(&sP[2][2 * tr + 1][vb]);
            const float4 g0 = *reinterpret_cast<const float4*>(&Gl[vb + 0][4 * tc]);
            const float4 g1 = *reinterpret_cast<const float4*>(&Gl[vb + 1][4 * tc]);
            const float4 g2 = *reinterpret_cast<const float4*>(&Gl[vb + 2][4 * tc]);
            const float4 g3 = *reinterpret_cast<const float4*>(&Gl[vb + 3][4 * tc]);

#define FMA_ONE(K, G) \
            acc[0]  += s0a.K * G.x; acc[1]  += s1a.K * G.x; acc[2]  += s2a.K * G.x; \
            acc[3]  += s0a.K * G.y; acc[4]  += s1a.K * G.y; acc[5]  += s2a.K * G.y; \
            acc[6]  += s0a.K * G.z; acc[7]  += s1a.K * G.z; acc[8]  += s2a.K * G.z; \
            acc[9]  += s0a.K * G.w; acc[10] += s1a.K * G.w; acc[11] += s2a.K * G.w; \
            acc[12] += s0b.K * G.x; acc[13] += s1b.K * G.x; acc[14] += s2b.K * G.x; \
            acc[15] += s0b.K * G.y; acc[16] += s1b.K * G.y; acc[17] += s2b.K * G.y; \
            acc[18] += s0b.K * G.z; acc[19] += s1b.K * G.z; acc[20] += s2b.K * G.z; \
            acc[21] += s0b.K * G.w; acc[22] += s1b.K * G.w; acc[23] += s2b.K * G.w;

            FMA_ONE(x, g0)
            FMA_ONE(y, g1)
            FMA_ONE(z, g2)
            FMA_ONE(w, g3)
#undef FMA_ONE
        }
    }

    // ---- write 24 outputs: 2 rows x 12 consecutive floats (GUARD col < NCOLS) ----
    float* outbase = ATOMIC ? dst : dst + (size_t)ks * CCX_ELEMS;
    const int colbase = c0 + 4 * tc;
    if (colbase < NCOLS) {             // threads fully in or fully out (480 % 4 == 0)
        #pragma unroll
        for (int dr = 0; dr < 2; ++dr) {
            const int r = r0 + 2 * tr + dr;
            if (r >= NROWS) continue;
            const size_t base = (size_t)r * RL + (size_t)colbase * 3;
            if (ATOMIC) {
                #pragma unroll
                for (int u = 0; u < 12; ++u)
                    atomicAdd(&outbase[base + u], acc[dr * 12 + u]);
            } else {
                const int a0 = dr * 12;
                float4 w0 = {acc[a0+0], acc[a0+1], acc[a0+2],  acc[a0+3]};
                float4 w1 = {acc[a0+4], acc[a0+5], acc[a0+6],  acc[a0+7]};
                float4 w2 = {acc[a0+8], acc[a0+9], acc[a0+10], acc[a0+11]};
                *reinterpret_cast<float4*>(&outbase[base + 0]) = w0;
                *reinterpret_cast<float4*>(&outbase[base + 4]) = w1;
                *reinterpret_cast<float4*>(&outbase[base + 8]) = w2;
            }
        }
    }
}

// ---------------------------------------------------------------------------
// Reduce: CCX[i] = sum_ks part[ks*CCX_ELEMS + i]
// ---------------------------------------------------------------------------
__global__ __launch_bounds__(256) void smpl_reduce(
    const float* __restrict__ part, float* __restrict__ CCX)
{
    const int i = (blockIdx.x * 256 + threadIdx.x) * 4;
    if (i >= CCX_ELEMS) return;
    float4 s = {0.f, 0.f, 0.f, 0.f};
    #pragma unroll 8
    for (int ks = 0; ks < KSPLIT; ++ks) {
        const float4 p = *reinterpret_cast<const float4*>(&part[(size_t)ks * CCX_ELEMS + i]);
        s.x += p.x; s.y += p.y; s.z += p.z; s.w += p.w;
    }
    *reinterpret_cast<float4*>(&CCX[i]) = s;
}

// ---------------------------------------------------------------------------
// Kernel B: one block per batch item (unchanged — passed round 1).
// ---------------------------------------------------------------------------
__global__ __launch_bounds__(256) void smpl_batch(
    const float* __restrict__ beta,
    const float* __restrict__ theta,
    const float* __restrict__ CCX,
    float* __restrict__ out)
{
    __shared__ float xs[218];
    __shared__ float Rl[24][9];
    __shared__ float Rg[24][9];
    __shared__ float tg[24][3];
    __shared__ float tA[24][3];
    __shared__ float Jl[24][3];
    __shared__ float Ml[1368];

    const int b = blockIdx.x;
    const int t = threadIdx.x;

    if (t < 24) {
        const int i = t;
        const float tx = theta[b * 72 + 3 * i + 0];
        const float ty = theta[b * 72 + 3 * i + 1];
        const float tz = theta[b * 72 + 3 * i + 2];
        const float ax = tx + 1e-8f, ay = ty + 1e-8f, az = tz + 1e-8f;
        const float angle = sqrtf(ax * ax + ay * ay + az * az);
        const float half = 0.5f * angle;
        const float sh = sinf(half), chh = cosf(half);
        const float inv = 1.f / angle;
        float qw = chh, qx = sh * tx * inv, qy = sh * ty * inv, qz = sh * tz * inv;
        const float rn = 1.f / sqrtf(qw * qw + qx * qx + qy * qy + qz * qz);
        qw *= rn; qx *= rn; qy *= rn; qz *= rn;
        float R[9];
        R[0] = 1.f - 2.f * (qy * qy + qz * qz);
        R[1] = 2.f * (qx * qy - qw * qz);
        R[2] = 2.f * (qx * qz + qw * qy);
        R[3] = 2.f * (qx * qy + qw * qz);
        R[4] = 1.f - 2.f * (qx * qx + qz * qz);
        R[5] = 2.f * (qy * qz - qw * qx);
        R[6] = 2.f * (qx * qz - qw * qy);
        R[7] = 2.f * (qy * qz + qw * qx);
        R[8] = 1.f - 2.f * (qx * qx + qy * qy);
        #pragma unroll
        for (int e = 0; e < 9; ++e) Rl[i][e] = R[e];
        if (i >= 1) {
            #pragma unroll
            for (int e = 0; e < 9; ++e)
                xs[11 + (i - 1) * 9 + e] = R[e] - ((e == 0 || e == 4 || e == 8) ? 1.f : 0.f);
        }
    } else if (t == 24) {
        xs[0] = 1.f;
    } else if (t >= 25 && t < 35) {
        xs[t - 24] = beta[b * NB + (t - 25)];
    }
    __syncthreads();

    if (t < 72) {
        const int jj = t / 3, c = t - jj * 3;
        float a = 0.f;
        #pragma unroll
        for (int r = 0; r <= 10; ++r)
            a += xs[r] * CCX[(size_t)r * RL + (456 + jj) * 3 + c];
        Jl[jj][c] = a;
    }
    __syncthreads();

    for (int lv = 0; lv < 9; ++lv) {
        const int beg = c_LOFF[lv];
        const int cnt = c_LOFF[lv + 1] - beg;
        if (t < cnt * 12) {
            const int li = t / 12, e = t - li * 12;
            const int j = beg + li;
            const int r = e >> 2, cc = e & 3;
            if (lv == 0) {
                if (cc < 3) Rg[0][r * 3 + cc] = Rl[0][r * 3 + cc] * ((cc == 0) ? 1.f : -1.f);
                else        tg[0][r] = Jl[0][r];
            } else {
                const int p = c_PAR[j];
                if (cc < 3) {
                    Rg[j][r * 3 + cc] = Rg[p][r * 3 + 0] * Rl[j][0 + cc]
                                      + Rg[p][r * 3 + 1] * Rl[j][3 + cc]
                                      + Rg[p][r * 3 + 2] * Rl[j][6 + cc];
                } else {
                    const float t0 = Jl[j][0] - Jl[p][0];
                    const float t1 = Jl[j][1] - Jl[p][1];
                    const float t2 = Jl[j][2] - Jl[p][2];
                    tg[j][r] = Rg[p][r * 3 + 0] * t0 + Rg[p][r * 3 + 1] * t1
                             + Rg[p][r * 3 + 2] * t2 + tg[p][r];
                }
            }
        }
        __syncthreads();
    }

    if (t < 72) {
        const int i = t / 3, c = t - (t / 3) * 3;
        tA[i][c] = tg[i][c] - (Rg[i][c * 3 + 0] * Jl[i][0]
                             + Rg[i][c * 3 + 1] * Jl[i][1]
                             + Rg[i][c * 3 + 2] * Jl[i][2]);
    }
    __syncthreads();

    {
        float a0 = 0, a1 = 0, a2 = 0, a3 = 0, a4 = 0, a5 = 0;
        #pragma unroll 4
        for (int r = 0; r < 218; ++r) {
            const float xv = xs[r];
            const float* row = CCX + (size_t)r * RL + t;
            a0 += xv * row[0];
            a1 += xv * row[256];
            a2 += xv * row[512];
            a3 += xv * row[768];
            a4 += xv * row[1024];
            a5 += xv * row[1280];
        }
        Ml[t] = a0;
        Ml[t + 256] = a1;
        Ml[t + 512] = a2;
        Ml[t + 768] = a3;
        Ml[t + 1024] = a4;
        if (t < 88) Ml[t + 1280] = a5;
    }
    __syncthreads();

    if (t < 57) {
        const int j = t / 3, c = t - (t / 3) * 3;
        float a = 0.f;
        #pragma unroll
        for (int i = 0; i < 24; ++i) {
            const int mb = (j * 24 + i) * 3;
            a += Rg[i][c * 3 + 0] * Ml[mb + 0]
               + Rg[i][c * 3 + 1] * Ml[mb + 1]
               + Rg[i][c * 3 + 2] * Ml[mb + 2]
               + tA[i][c] * CCX[(size_t)218 * RL + mb];
        }
        out[b * 57 + t] = a;
    }
}

extern "C" void kernel_launch(void* const* d_in, const int* in_sizes, int n_in,
                              void* d_out, int out_size, void* d_ws, size_t ws_size,
                              hipStream_t stream) {
    const float* beta  = (const float*)d_in[0];
    const float* theta = (const float*)d_in[1];
    const float* vt    = (const float*)d_in[2];
    const float* sd    = (const float*)d_in[3];
    const float* pd    = (const float*)d_in[4];
    const float* Jreg  = (const float*)d_in[5];
    const float* jr    = (const float*)d_in[6];
    const float* w     = (const float*)d_in[7];
    float* outp = (float*)d_out;
    float* CCX  = (float*)d_ws;

    const size_t need = (size_t)(KSPLIT + 1) * CCX_ELEMS * sizeof(float);
    if (ws_size >= need) {
        float* part = CCX + CCX_ELEMS;
        smpl_pre<false><<<1792, 256, 0, stream>>>(vt, sd, pd, Jreg, jr, w, part);
        smpl_reduce<<<(CCX_ELEMS / 4 + 255) / 256, 256, 0, stream>>>(part, CCX);
    } else {
        hipMemsetAsync(CCX, 0, CCX_ELEMS * sizeof(float), stream);
        smpl_pre<true><<<1792, 256, 0, stream>>>(vt, sd, pd, Jreg, jr, w, CCX);
    }
    smpl_batch<<<512, 256, 0, stream>>>(beta, theta, CCX, outp);
}

// Round 4
// 146.612 us; speedup vs baseline: 2.2447x; 2.2447x over previous
//
#include <hip/hip_runtime.h>
#include <hip/hip_bf16.h>

#define VNUM 6890
#define SLEN 20670      // V*3
#define NJ 24
#define NJR 19
#define NB 10
#define NROWS 219
#define NCOLS 480
#define RL 1440         // NCOLS*3
#define CCX_ELEMS (NROWS * RL)   // 315360 floats

// GEMM geometry: M = 3*219 -> 672 (21 tiles of 32), N = 480 -> 512 (2 tiles
// of 256), K = 6890 -> 6912 (216 chunks of 32). A'[m=3r+c][k=v] = s_r[3v+c].
#define MDIM 672
#define MT   21
#define NT   2
#define KC   216        // k-chunks of 32
#define KSPLIT 12
#define KCP  18         // KC / KSPLIT
#define AROW 40         // k-padded row length (32 data + 8 pad) in bf16
#define AIMG (32 * AROW)    // 1280 shorts = 2560 B per (mt,kc) image
#define BIMG (256 * AROW)   // 10240 shorts = 20480 B per (nt,kc) image

typedef short short8 __attribute__((ext_vector_type(8)));
typedef float f32x4 __attribute__((ext_vector_type(4)));

#define GLOAD_LDS16(g, l) \
    __builtin_amdgcn_global_load_lds((const __attribute__((address_space(1))) void*)(g), \
                                     (__attribute__((address_space(3))) void*)(l), 16, 0, 0)

__constant__ int c_PAR[24]  = {0,0,0,0,1,2,3,4,5,6,7,8,9,9,9,12,13,14,16,17,18,19,20,21};
__constant__ int c_LOFF[10] = {0,1,4,7,10,15,18,20,22,24};

__device__ __forceinline__ unsigned short f2bf(float f) {
    union { float f; unsigned int u; } x; x.f = f;
    unsigned int r = x.u + 0x7fffu + ((x.u >> 16) & 1u);   // RNE
    return (unsigned short)(r >> 16);
}

// ---------------------------------------------------------------------------
// packA: one block per r (0..223). Writes Apack[((mt*KC+kc)*32+mrow)*AROW+kk].
// ---------------------------------------------------------------------------
__global__ __launch_bounds__(256) void packA(
    const float* __restrict__ vt, const float* __restrict__ sd,
    const float* __restrict__ pd, unsigned short* __restrict__ Apack)
{
    const int r = blockIdx.x;          // 0..223
    const int t = threadIdx.x;
    const float* src = nullptr;
    if (r == 0) src = vt;
    else if (r <= 10) src = sd + (size_t)(r - 1) * SLEN;
    else if (r <= 217) src = pd + (size_t)(r - 11) * SLEN;
    for (int e = t; e < 3 * 6912; e += 256) {
        const int c = e / 6912;
        const int k = e - c * 6912;
        float val = 0.f;
        if (r <= 217 && k < VNUM) val = src[3 * k + c];
        else if (r == 218 && k < VNUM) val = 1.f;
        const int m = 3 * r + c;
        const int mt = m >> 5, mrow = m & 31, kc = k >> 5, kk = k & 31;
        Apack[((size_t)(mt * KC + kc) * 32 + mrow) * AROW + kk] = f2bf(val);
    }
}

// ---------------------------------------------------------------------------
// packB: one block per kc (216). B[v][col] = jr[v,col/24]*w[v,col%24] (col<456)
//        or Jreg[v,col-456] (456..479), 0 otherwise. K-transposed padded tiles.
// ---------------------------------------------------------------------------
__global__ __launch_bounds__(256) void packB(
    const float* __restrict__ Jreg, const float* __restrict__ jr,
    const float* __restrict__ w, unsigned short* __restrict__ Bpack)
{
    __shared__ float jrl[32 * NJR];   // 608
    __shared__ float wl[32 * NJ];     // 768
    __shared__ float Jl2[32 * NJ];    // 768
    const int kc = blockIdx.x;
    const int t = threadIdx.x;
    const int v0 = kc * 32;
    for (int i = t; i < 32 * NJR; i += 256) {
        const int g = v0 * NJR + i;
        jrl[i] = (g < VNUM * NJR) ? jr[g] : 0.f;
    }
    for (int i = t; i < 32 * NJ; i += 256) {
        const int g = v0 * NJ + i;
        wl[i]  = (g < VNUM * NJ) ? w[g] : 0.f;
        Jl2[i] = (g < VNUM * NJ) ? Jreg[g] : 0.f;
    }
    __syncthreads();
    #pragma unroll
    for (int nt = 0; nt < NT; ++nt) {
        const int col = nt * 256 + t;
        const int j = col / 24, i = col - j * 24;
        unsigned short tmp[32];
        #pragma unroll 8
        for (int kk = 0; kk < 32; ++kk) {
            float val = 0.f;
            if (v0 + kk < VNUM) {
                if (col < 456)      val = jrl[kk * NJR + j] * wl[kk * NJ + i];
                else if (col < 480) val = Jl2[kk * NJ + (col - 456)];
            }
            tmp[kk] = f2bf(val);
        }
        unsigned short* dst = Bpack + ((size_t)(nt * KC + kc) * 256 + t) * AROW;
        #pragma unroll
        for (int kk = 0; kk < 32; kk += 8)
            *reinterpret_cast<short8*>(dst + kk) = *reinterpret_cast<short8*>(tmp + kk);
    }
}

// ---------------------------------------------------------------------------
// gemm: 504 blocks = 21 mt x 2 nt x 12 ksplit. Block tile 32x256, 4 waves:
// wave w -> rows 16*(w&1), cols 128*(w>>1); 8 frags of 16x16 per wave.
// LDS double-buffered A(2.5KB)+B(20KB) images staged via global_load_lds.
// ---------------------------------------------------------------------------
__global__ __launch_bounds__(256) void gemm_mfma(
    const unsigned short* __restrict__ Apack,
    const unsigned short* __restrict__ Bpack,
    float* __restrict__ partials)
{
    __shared__ __align__(16) char smem[2 * 2560 + 2 * 20480];  // 46080 B
    const int AOFF[2] = {0, 2560};
    const int BOFF[2] = {5120, 5120 + 20480};

    const int bid = blockIdx.x;
    const int ks = bid % KSPLIT;
    const int nt = (bid / KSPLIT) & 1;
    const int mt = bid / (KSPLIT * NT);
    const int t = threadIdx.x;
    const int w = t >> 6;
    const int lane15 = t & 15;
    const int kg = (t >> 4) & 3;       // (lane>>4): k-group 0..3
    const int mrow0 = (w & 1) * 16;
    const int ncol0 = (w >> 1) * 128;

    const int kc0 = ks * KCP;
    const char* Abase = (const char*)(Apack + (size_t)mt * KC * AIMG);
    const char* Bbase = (const char*)(Bpack + (size_t)nt * KC * BIMG);

#define STAGE(kc, buf) do { \
        const char* ga = Abase + (size_t)(kc) * 2560; \
        const char* gb = Bbase + (size_t)(kc) * 20480; \
        if (t < 160) GLOAD_LDS16(ga + t * 16, smem + AOFF[buf] + (t >> 6) * 1024); \
        _Pragma("unroll") \
        for (int it = 0; it < 5; ++it) \
            GLOAD_LDS16(gb + (it * 256 + t) * 16, smem + BOFF[buf] + it * 4096 + (t >> 6) * 1024); \
    } while (0)

    f32x4 acc[8];
    #pragma unroll
    for (int f = 0; f < 8; ++f) acc[f] = (f32x4){0.f, 0.f, 0.f, 0.f};

    STAGE(kc0, 0);
    asm volatile("s_waitcnt vmcnt(0)" ::: "memory");
    __syncthreads();

    for (int i = 0; i < KCP; ++i) {
        const int cur = i & 1;
        if (i < KCP - 1) STAGE(kc0 + i + 1, cur ^ 1);

        const char* al = smem + AOFF[cur] + (mrow0 + lane15) * (AROW * 2) + kg * 16;
        const short8 af = *reinterpret_cast<const short8*>(al);
        const char* bl = smem + BOFF[cur] + (ncol0 + lane15) * (AROW * 2) + kg * 16;
        #pragma unroll
        for (int f = 0; f < 8; ++f) {
            const short8 bf = *reinterpret_cast<const short8*>(bl + f * 16 * (AROW * 2));
            acc[f] = __builtin_amdgcn_mfma_f32_16x16x32_bf16(af, bf, acc[f], 0, 0, 0);
        }
        if (i < KCP - 1) {
            asm volatile("s_waitcnt vmcnt(0)" ::: "memory");
            __syncthreads();
        }
    }

    // write partial tile: partials[ks][m][col], m = mt*32 + mrow0 + kg*4 + reg
    #pragma unroll
    for (int f = 0; f < 8; ++f) {
        const int col = nt * 256 + ncol0 + f * 16 + lane15;
        const int mb = mt * 32 + mrow0 + kg * 4;
        #pragma unroll
        for (int reg = 0; reg < 4; ++reg)
            partials[((size_t)ks * MDIM + mb + reg) * 512 + col] = acc[f][reg];
    }
#undef STAGE
}

// ---------------------------------------------------------------------------
// reduce: CCX[r][col*3+c] = sum_ks partials[ks][3r+c][col]
// ---------------------------------------------------------------------------
__global__ __launch_bounds__(256) void reduce_part(
    const float* __restrict__ partials, float* __restrict__ CCX)
{
    const int idx = blockIdx.x * 256 + threadIdx.x;   // (m, col4)
    const int m = idx >> 7;
    const int col = (idx & 127) * 4;
    if (m >= MDIM) return;
    float4 s = {0.f, 0.f, 0.f, 0.f};
    #pragma unroll
    for (int ks = 0; ks < KSPLIT; ++ks) {
        const float4 p = *reinterpret_cast<const float4*>(
            &partials[((size_t)ks * MDIM + m) * 512 + col]);
        s.x += p.x; s.y += p.y; s.z += p.z; s.w += p.w;
    }
    if (m < 657 && col < NCOLS) {
        const int r = m / 3, c = m - r * 3;
        float sv[4] = {s.x, s.y, s.z, s.w};
        #pragma unroll
        for (int u = 0; u < 4; ++u)
            CCX[(size_t)r * RL + (col + u) * 3 + c] = sv[u];
    }
}

// ---------------------------------------------------------------------------
// fp32 exact recompute of CCX rows 0 (v_template) and 218 (ones): one block
// per col. Overwrites the bf16 results for those rows.
// ---------------------------------------------------------------------------
__global__ __launch_bounds__(256) void fp32_rows(
    const float* __restrict__ vt, const float* __restrict__ Jreg,
    const float* __restrict__ jr, const float* __restrict__ w,
    float* __restrict__ CCX)
{
    __shared__ float red[4][4];
    const int col = blockIdx.x;
    const int t = threadIdx.x;
    const int j = col / 24, i = col - j * 24;
    float a0 = 0.f, a1 = 0.f, a2 = 0.f, a3 = 0.f;
    for (int v = t; v < VNUM; v += 256) {
        const float coef = (col < 456) ? jr[v * NJR + j] * w[v * NJ + i]
                                       : Jreg[v * NJ + (col - 456)];
        a0 += coef * vt[3 * v + 0];
        a1 += coef * vt[3 * v + 1];
        a2 += coef * vt[3 * v + 2];
        a3 += coef;
    }
    #pragma unroll
    for (int off = 32; off; off >>= 1) {
        a0 += __shfl_down(a0, off);
        a1 += __shfl_down(a1, off);
        a2 += __shfl_down(a2, off);
        a3 += __shfl_down(a3, off);
    }
    if ((t & 63) == 0) {
        red[t >> 6][0] = a0; red[t >> 6][1] = a1;
        red[t >> 6][2] = a2; red[t >> 6][3] = a3;
    }
    __syncthreads();
    if (t == 0) {
        float s0 = 0, s1 = 0, s2 = 0, s3 = 0;
        #pragma unroll
        for (int u = 0; u < 4; ++u) {
            s0 += red[u][0]; s1 += red[u][1]; s2 += red[u][2]; s3 += red[u][3];
        }
        CCX[col * 3 + 0] = s0;
        CCX[col * 3 + 1] = s1;
        CCX[col * 3 + 2] = s2;
        CCX[(size_t)218 * RL + col * 3 + 0] = s3;
        CCX[(size_t)218 * RL + col * 3 + 1] = s3;
        CCX[(size_t)218 * RL + col * 3 + 2] = s3;
    }
}

// ---------------------------------------------------------------------------
// Kernel B: one block per batch item (unchanged — verified).
// ---------------------------------------------------------------------------
__global__ __launch_bounds__(256) void smpl_batch(
    const float* __restrict__ beta,
    const float* __restrict__ theta,
    const float* __restrict__ CCX,
    float* __restrict__ out)
{
    __shared__ float xs[218];
    __shared__ float Rl[24][9];
    __shared__ float Rg[24][9];
    __shared__ float tg[24][3];
    __shared__ float tA[24][3];
    __shared__ float Jl[24][3];
    __shared__ float Ml[1368];

    const int b = blockIdx.x;
    const int t = threadIdx.x;

    if (t < 24) {
        const int i = t;
        const float tx = theta[b * 72 + 3 * i + 0];
        const float ty = theta[b * 72 + 3 * i + 1];
        const float tz = theta[b * 72 + 3 * i + 2];
        const float ax = tx + 1e-8f, ay = ty + 1e-8f, az = tz + 1e-8f;
        const float angle = sqrtf(ax * ax + ay * ay + az * az);
        const float half = 0.5f * angle;
        const float sh = sinf(half), chh = cosf(half);
        const float inv = 1.f / angle;
        float qw = chh, qx = sh * tx * inv, qy = sh * ty * inv, qz = sh * tz * inv;
        const float rn = 1.f / sqrtf(qw * qw + qx * qx + qy * qy + qz * qz);
        qw *= rn; qx *= rn; qy *= rn; qz *= rn;
        float R[9];
        R[0] = 1.f - 2.f * (qy * qy + qz * qz);
        R[1] = 2.f * (qx * qy - qw * qz);
        R[2] = 2.f * (qx * qz + qw * qy);
        R[3] = 2.f * (qx * qy + qw * qz);
        R[4] = 1.f - 2.f * (qx * qx + qz * qz);
        R[5] = 2.f * (qy * qz - qw * qx);
        R[6] = 2.f * (qx * qz - qw * qy);
        R[7] = 2.f * (qy * qz + qw * qx);
        R[8] = 1.f - 2.f * (qx * qx + qy * qy);
        #pragma unroll
        for (int e = 0; e < 9; ++e) Rl[i][e] = R[e];
        if (i >= 1) {
            #pragma unroll
            for (int e = 0; e < 9; ++e)
                xs[11 + (i - 1) * 9 + e] = R[e] - ((e == 0 || e == 4 || e == 8) ? 1.f : 0.f);
        }
    } else if (t == 24) {
        xs[0] = 1.f;
    } else if (t >= 25 && t < 35) {
        xs[t - 24] = beta[b * NB + (t - 25)];
    }
    __syncthreads();

    if (t < 72) {
        const int jj = t / 3, c = t - jj * 3;
        float a = 0.f;
        #pragma unroll
        for (int r = 0; r <= 10; ++r)
            a += xs[r] * CCX[(size_t)r * RL + (456 + jj) * 3 + c];
        Jl[jj][c] = a;
    }
    __syncthreads();

    for (int lv = 0; lv < 9; ++lv) {
        const int beg = c_LOFF[lv];
        const int cnt = c_LOFF[lv + 1] - beg;
        if (t < cnt * 12) {
            const int li = t / 12, e = t - li * 12;
            const int j = beg + li;
            const int r = e >> 2, cc = e & 3;
            if (lv == 0) {
                if (cc < 3) Rg[0][r * 3 + cc] = Rl[0][r * 3 + cc] * ((cc == 0) ? 1.f : -1.f);
                else        tg[0][r] = Jl[0][r];
            } else {
                const int p = c_PAR[j];
                if (cc < 3) {
                    Rg[j][r * 3 + cc] = Rg[p][r * 3 + 0] * Rl[j][0 + cc]
                                      + Rg[p][r * 3 + 1] * Rl[j][3 + cc]
                                      + Rg[p][r * 3 + 2] * Rl[j][6 + cc];
                } else {
                    const float t0 = Jl[j][0] - Jl[p][0];
                    const float t1 = Jl[j][1] - Jl[p][1];
                    const float t2 = Jl[j][2] - Jl[p][2];
                    tg[j][r] = Rg[p][r * 3 + 0] * t0 + Rg[p][r * 3 + 1] * t1
                             + Rg[p][r * 3 + 2] * t2 + tg[p][r];
                }
            }
        }
        __syncthreads();
    }

    if (t < 72) {
        const int i = t / 3, c = t - (t / 3) * 3;
        tA[i][c] = tg[i][c] - (Rg[i][c * 3 + 0] * Jl[i][0]
                             + Rg[i][c * 3 + 1] * Jl[i][1]
                             + Rg[i][c * 3 + 2] * Jl[i][2]);
    }
    __syncthreads();

    {
        float a0 = 0, a1 = 0, a2 = 0, a3 = 0, a4 = 0, a5 = 0;
        #pragma unroll 4
        for (int r = 0; r < 218; ++r) {
            const float xv = xs[r];
            const float* row = CCX + (size_t)r * RL + t;
            a0 += xv * row[0];
            a1 += xv * row[256];
            a2 += xv * row[512];
            a3 += xv * row[768];
            a4 += xv * row[1024];
            a5 += xv * row[1280];
        }
        Ml[t] = a0;
        Ml[t + 256] = a1;
        Ml[t + 512] = a2;
        Ml[t + 768] = a3;
        Ml[t + 1024] = a4;
        if (t < 88) Ml[t + 1280] = a5;
    }
    __syncthreads();

    if (t < 57) {
        const int j = t / 3, c = t - (t / 3) * 3;
        float a = 0.f;
        #pragma unroll
        for (int i = 0; i < 24; ++i) {
            const int mb = (j * 24 + i) * 3;
            a += Rg[i][c * 3 + 0] * Ml[mb + 0]
               + Rg[i][c * 3 + 1] * Ml[mb + 1]
               + Rg[i][c * 3 + 2] * Ml[mb + 2]
               + tA[i][c] * CCX[(size_t)218 * RL + mb];
        }
        out[b * 57 + t] = a;
    }
}

extern "C" void kernel_launch(void* const* d_in, const int* in_sizes, int n_in,
                              void* d_out, int out_size, void* d_ws, size_t ws_size,
                              hipStream_t stream) {
    const float* beta  = (const float*)d_in[0];
    const float* theta = (const float*)d_in[1];
    const float* vt    = (const float*)d_in[2];
    const float* sd    = (const float*)d_in[3];
    const float* pd    = (const float*)d_in[4];
    const float* Jreg  = (const float*)d_in[5];
    const float* jr    = (const float*)d_in[6];
    const float* w     = (const float*)d_in[7];
    float* outp = (float*)d_out;

    // ws layout (floats): CCX[315360] | partials[12*672*512] | Apack | Bpack
    float* CCX = (float*)d_ws;
    float* partials = CCX + CCX_ELEMS;
    unsigned short* Apack = (unsigned short*)(partials + (size_t)KSPLIT * MDIM * 512);
    unsigned short* Bpack = Apack + (size_t)MT * KC * AIMG;

    packA<<<224, 256, 0, stream>>>(vt, sd, pd, Apack);
    packB<<<KC, 256, 0, stream>>>(Jreg, jr, w, Bpack);
    gemm_mfma<<<MT * NT * KSPLIT, 256, 0, stream>>>(Apack, Bpack, partials);
    reduce_part<<<(MDIM * 128 + 255) / 256, 256, 0, stream>>>(partials, CCX);
    fp32_rows<<<NCOLS, 256, 0, stream>>>(vt, Jreg, jr, w, CCX);
    smpl_batch<<<512, 256, 0, stream>>>(beta, theta, CCX, outp);
}

// Round 6
// 97.961 us; speedup vs baseline: 3.3594x; 1.4966x over previous
//
#include <hip/hip_runtime.h>
#include <hip/hip_bf16.h>

#define VNUM 6890
#define SLEN 20670      // V*3
#define NJ 24
#define NJR 19
#define NB 10
#define NROWS 219
#define NCOLS 480
#define RL 1440         // NCOLS*3
#define CCX_ELEMS (NROWS * RL)   // 315360 floats

// GEMM geometry: M = 3*219 -> 672 (21 tiles of 32), N = 480 -> 512 (2 tiles
// of 256), K = 6890 -> 6912 (216 chunks of 32). A'[m=3r+c][k=v] = s_r[3v+c].
#define MDIM 672
#define MT   21
#define NT   2
#define KC   216        // k-chunks of 32
#define KSPLIT 12
#define KCP  18         // KC / KSPLIT
#define AROW 40         // k-padded row length (32 data + 8 pad) in bf16
#define AIMG (32 * AROW)    // per (mt,kc) image, shorts
#define BIMG (256 * AROW)   // per (nt,kc) image, shorts

typedef short short8 __attribute__((ext_vector_type(8)));
typedef unsigned short u16x4 __attribute__((ext_vector_type(4)));
typedef float f32x4 __attribute__((ext_vector_type(4)));

#define GLOAD_LDS16(g, l) \
    __builtin_amdgcn_global_load_lds((const __attribute__((address_space(1))) void*)(g), \
                                     (__attribute__((address_space(3))) void*)(l), 16, 0, 0)

__constant__ int c_PAR[24]  = {0,0,0,0,1,2,3,4,5,6,7,8,9,9,9,12,13,14,16,17,18,19,20,21};
__constant__ int c_LOFF[10] = {0,1,4,7,10,15,18,20,22,24};

__device__ __forceinline__ unsigned short f2bf(float f) {
    union { float f; unsigned int u; } x; x.f = f;
    unsigned int r = x.u + 0x7fffu + ((x.u >> 16) & 1u);   // RNE
    return (unsigned short)(r >> 16);
}

// ---------------------------------------------------------------------------
// prep: fused packA (bid<224) | packB (bid<440) | fp32_rows (bid<920).
// ---------------------------------------------------------------------------
__global__ __launch_bounds__(256) void prep(
    const float* __restrict__ vt, const float* __restrict__ sd,
    const float* __restrict__ pd, const float* __restrict__ Jreg,
    const float* __restrict__ jr, const float* __restrict__ w,
    unsigned short* __restrict__ Apack, unsigned short* __restrict__ Bpack,
    float* __restrict__ CCX)
{
    __shared__ float jrl[32 * NJR];
    __shared__ float wl[32 * NJ];
    __shared__ float Jl2[32 * NJ];
    __shared__ float red[4][4];

    const int bid = blockIdx.x;
    const int t = threadIdx.x;

    if (bid < 224) {
        // ---------------- packA: one block per r ----------------
        const int r = bid;
        const float* src = (r == 0) ? vt
                         : (r <= 10 ? sd + (size_t)(r - 1) * SLEN
                         : (r <= 217 ? pd + (size_t)(r - 11) * SLEN : nullptr));
        for (int g = t; g < 1728; g += 256) {     // groups of 4 vertices
            const int v = 4 * g;
            float lv[12];
            if (r <= 217) {
                if (3 * v + 12 <= SLEN) {
                    const float4 a = *reinterpret_cast<const float4*>(src + 3 * v);
                    const float4 b4 = *reinterpret_cast<const float4*>(src + 3 * v + 4);
                    const float4 c4 = *reinterpret_cast<const float4*>(src + 3 * v + 8);
                    lv[0]=a.x; lv[1]=a.y; lv[2]=a.z; lv[3]=a.w;
                    lv[4]=b4.x; lv[5]=b4.y; lv[6]=b4.z; lv[7]=b4.w;
                    lv[8]=c4.x; lv[9]=c4.y; lv[10]=c4.z; lv[11]=c4.w;
                } else {
                    #pragma unroll
                    for (int l = 0; l < 12; ++l) {
                        const int idx = 3 * v + l;
                        lv[l] = (idx < SLEN) ? src[idx] : 0.f;
                    }
                }
            } else if (r == 218) {
                #pragma unroll
                for (int l = 0; l < 12; ++l) lv[l] = (v + l / 3 < VNUM) ? 1.f : 0.f;
            } else {
                #pragma unroll
                for (int l = 0; l < 12; ++l) lv[l] = 0.f;
            }
            const int kc = v >> 5, kk = v & 31;
            #pragma unroll
            for (int c = 0; c < 3; ++c) {
                const int m = 3 * r + c;
                const int mt = m >> 5, mrow = m & 31;
                u16x4 s = {f2bf(lv[c]), f2bf(lv[3 + c]), f2bf(lv[6 + c]), f2bf(lv[9 + c])};
                *reinterpret_cast<u16x4*>(
                    &Apack[((size_t)(mt * KC + kc) * 32 + mrow) * AROW + kk]) = s;
            }
        }
    } else if (bid < 440) {
        // ---------------- packB: one block per kc ----------------
        const int kc = bid - 224;
        const int v0 = kc * 32;
        for (int i = t; i < 32 * NJR; i += 256) {
            const int g = v0 * NJR + i;
            jrl[i] = (g < VNUM * NJR) ? jr[g] : 0.f;
        }
        for (int i = t; i < 32 * NJ; i += 256) {
            const int g = v0 * NJ + i;
            wl[i]  = (g < VNUM * NJ) ? w[g] : 0.f;
            Jl2[i] = (g < VNUM * NJ) ? Jreg[g] : 0.f;
        }
        __syncthreads();
        #pragma unroll
        for (int nt = 0; nt < NT; ++nt) {
            const int col = nt * 256 + t;
            const int j = col / 24, i = col - j * 24;
            short8 ov[4];   // constant-indexed -> stays in registers
            #pragma unroll
            for (int kk = 0; kk < 32; ++kk) {
                float val = 0.f;
                if (v0 + kk < VNUM) {
                    if (col < 456)      val = jrl[kk * NJR + j] * wl[kk * NJ + i];
                    else if (col < 480) val = Jl2[kk * NJ + (col - 456)];
                }
                ov[kk >> 3][kk & 7] = (short)f2bf(val);
            }
            unsigned short* dst = Bpack + ((size_t)(nt * KC + kc) * 256 + t) * AROW;
            #pragma unroll
            for (int q = 0; q < 4; ++q)
                *reinterpret_cast<short8*>(dst + 8 * q) = ov[q];
        }
    } else {
        // ------------- fp32_rows: exact rows 0 and 218 of CCX -------------
        const int col = bid - 440;                 // 0..479
        const int j = col / 24, i = col - j * 24;
        float a0 = 0.f, a1 = 0.f, a2 = 0.f, a3 = 0.f;
        for (int v = t; v < VNUM; v += 256) {
            const float coef = (col < 456) ? jr[v * NJR + j] * w[v * NJ + i]
                                           : Jreg[v * NJ + (col - 456)];
            a0 += coef * vt[3 * v + 0];
            a1 += coef * vt[3 * v + 1];
            a2 += coef * vt[3 * v + 2];
            a3 += coef;
        }
        #pragma unroll
        for (int off = 32; off; off >>= 1) {
            a0 += __shfl_down(a0, off);
            a1 += __shfl_down(a1, off);
            a2 += __shfl_down(a2, off);
            a3 += __shfl_down(a3, off);
        }
        if ((t & 63) == 0) {
            red[t >> 6][0] = a0; red[t >> 6][1] = a1;
            red[t >> 6][2] = a2; red[t >> 6][3] = a3;
        }
        __syncthreads();
        if (t == 0) {
            float s0 = 0, s1 = 0, s2 = 0, s3 = 0;
            #pragma unroll
            for (int u = 0; u < 4; ++u) {
                s0 += red[u][0]; s1 += red[u][1]; s2 += red[u][2]; s3 += red[u][3];
            }
            CCX[col * 3 + 0] = s0;
            CCX[col * 3 + 1] = s1;
            CCX[col * 3 + 2] = s2;
            CCX[(size_t)218 * RL + col * 3 + 0] = s3;
            CCX[(size_t)218 * RL + col * 3 + 1] = s3;
            CCX[(size_t)218 * RL + col * 3 + 2] = s3;
        }
    }
}

// ---------------------------------------------------------------------------
// gemm: 504 blocks = 21 mt x 2 nt x 12 ksplit (unchanged — verified round 4).
// ---------------------------------------------------------------------------
__global__ __launch_bounds__(256) void gemm_mfma(
    const unsigned short* __restrict__ Apack,
    const unsigned short* __restrict__ Bpack,
    float* __restrict__ partials)
{
    __shared__ __align__(16) char smem[2 * 2560 + 2 * 20480];
    const int AOFF[2] = {0, 2560};
    const int BOFF[2] = {5120, 5120 + 20480};

    const int bid = blockIdx.x;
    const int ks = bid % KSPLIT;
    const int nt = (bid / KSPLIT) & 1;
    const int mt = bid / (KSPLIT * NT);
    const int t = threadIdx.x;
    const int w = t >> 6;
    const int lane15 = t & 15;
    const int kg = (t >> 4) & 3;
    const int mrow0 = (w & 1) * 16;
    const int ncol0 = (w >> 1) * 128;

    const int kc0 = ks * KCP;
    const char* Abase = (const char*)(Apack + (size_t)mt * KC * AIMG);
    const char* Bbase = (const char*)(Bpack + (size_t)nt * KC * BIMG);

#define STAGE(kc, buf) do { \
        const char* ga = Abase + (size_t)(kc) * 2560; \
        const char* gb = Bbase + (size_t)(kc) * 20480; \
        if (t < 160) GLOAD_LDS16(ga + t * 16, smem + AOFF[buf] + (t >> 6) * 1024); \
        _Pragma("unroll") \
        for (int it = 0; it < 5; ++it) \
            GLOAD_LDS16(gb + (it * 256 + t) * 16, smem + BOFF[buf] + it * 4096 + (t >> 6) * 1024); \
    } while (0)

    f32x4 acc[8];
    #pragma unroll
    for (int f = 0; f < 8; ++f) acc[f] = (f32x4){0.f, 0.f, 0.f, 0.f};

    STAGE(kc0, 0);
    asm volatile("s_waitcnt vmcnt(0)" ::: "memory");
    __syncthreads();

    for (int i = 0; i < KCP; ++i) {
        const int cur = i & 1;
        if (i < KCP - 1) STAGE(kc0 + i + 1, cur ^ 1);

        const char* al = smem + AOFF[cur] + (mrow0 + lane15) * (AROW * 2) + kg * 16;
        const short8 af = *reinterpret_cast<const short8*>(al);
        const char* bl = smem + BOFF[cur] + (ncol0 + lane15) * (AROW * 2) + kg * 16;
        #pragma unroll
        for (int f = 0; f < 8; ++f) {
            const short8 bf = *reinterpret_cast<const short8*>(bl + f * 16 * (AROW * 2));
            acc[f] = __builtin_amdgcn_mfma_f32_16x16x32_bf16(af, bf, acc[f], 0, 0, 0);
        }
        if (i < KCP - 1) {
            asm volatile("s_waitcnt vmcnt(0)" ::: "memory");
            __syncthreads();
        }
    }

    #pragma unroll
    for (int f = 0; f < 8; ++f) {
        const int col = nt * 256 + ncol0 + f * 16 + lane15;
        const int mb = mt * 32 + mrow0 + kg * 4;
        #pragma unroll
        for (int reg = 0; reg < 4; ++reg)
            partials[((size_t)ks * MDIM + mb + reg) * 512 + col] = acc[f][reg];
    }
#undef STAGE
}

// ---------------------------------------------------------------------------
// reduce: CCX[r][col*3+c] = sum_ks partials[ks][3r+c][col]; SKIPS r==0,218
// (those are written exactly in fp32 by prep).
// ---------------------------------------------------------------------------
__global__ __launch_bounds__(256) void reduce_part(
    const float* __restrict__ partials, float* __restrict__ CCX)
{
    const int idx = blockIdx.x * 256 + threadIdx.x;
    const int m = idx >> 7;
    const int col = (idx & 127) * 4;
    if (m >= MDIM) return;
    float4 s = {0.f, 0.f, 0.f, 0.f};
    #pragma unroll
    for (int ks = 0; ks < KSPLIT; ++ks) {
        const float4 p = *reinterpret_cast<const float4*>(
            &partials[((size_t)ks * MDIM + m) * 512 + col]);
        s.x += p.x; s.y += p.y; s.z += p.z; s.w += p.w;
    }
    if (m < 657 && col < NCOLS) {
        const int r = m / 3, c = m - r * 3;
        if (r != 0 && r != 218) {
            float sv[4] = {s.x, s.y, s.z, s.w};
            #pragma unroll
            for (int u = 0; u < 4; ++u)
                CCX[(size_t)r * RL + (col + u) * 3 + c] = sv[u];
        }
    }
}

// ---------------------------------------------------------------------------
// chain: per-b rodrigues + J + kinematic chain + A. Writes xs/Rg/tA to ws.
// ---------------------------------------------------------------------------
__global__ __launch_bounds__(256) void chain_k(
    const float* __restrict__ beta,
    const float* __restrict__ theta,
    const float* __restrict__ CCX,
    float* __restrict__ xs_ws, float* __restrict__ Rg_ws, float* __restrict__ tA_ws)
{
    __shared__ float xs[218];
    __shared__ float Rl[24][9];
    __shared__ float Rg[24][9];
    __shared__ float tg[24][3];
    __shared__ float tA[24][3];
    __shared__ float Jl[24][3];

    const int b = blockIdx.x;
    const int t = threadIdx.x;

    if (t < 24) {
        const int i = t;
        const float tx = theta[b * 72 + 3 * i + 0];
        const float ty = theta[b * 72 + 3 * i + 1];
        const float tz = theta[b * 72 + 3 * i + 2];
        const float ax = tx + 1e-8f, ay = ty + 1e-8f, az = tz + 1e-8f;
        const float angle = sqrtf(ax * ax + ay * ay + az * az);
        const float half = 0.5f * angle;
        const float sh = sinf(half), chh = cosf(half);
        const float inv = 1.f / angle;
        float qw = chh, qx = sh * tx * inv, qy = sh * ty * inv, qz = sh * tz * inv;
        const float rn = 1.f / sqrtf(qw * qw + qx * qx + qy * qy + qz * qz);
        qw *= rn; qx *= rn; qy *= rn; qz *= rn;
        float R[9];
        R[0] = 1.f - 2.f * (qy * qy + qz * qz);
        R[1] = 2.f * (qx * qy - qw * qz);
        R[2] = 2.f * (qx * qz + qw * qy);
        R[3] = 2.f * (qx * qy + qw * qz);
        R[4] = 1.f - 2.f * (qx * qx + qz * qz);
        R[5] = 2.f * (qy * qz - qw * qx);
        R[6] = 2.f * (qx * qz - qw * qy);
        R[7] = 2.f * (qy * qz + qw * qx);
        R[8] = 1.f - 2.f * (qx * qx + qy * qy);
        #pragma unroll
        for (int e = 0; e < 9; ++e) Rl[i][e] = R[e];
        if (i >= 1) {
            #pragma unroll
            for (int e = 0; e < 9; ++e)
                xs[11 + (i - 1) * 9 + e] = R[e] - ((e == 0 || e == 4 || e == 8) ? 1.f : 0.f);
        }
    } else if (t == 24) {
        xs[0] = 1.f;
    } else if (t >= 25 && t < 35) {
        xs[t - 24] = beta[b * NB + (t - 25)];
    }
    __syncthreads();

    if (t < 72) {
        const int jj = t / 3, c = t - jj * 3;
        float a = 0.f;
        #pragma unroll
        for (int r = 0; r <= 10; ++r)
            a += xs[r] * CCX[(size_t)r * RL + (456 + jj) * 3 + c];
        Jl[jj][c] = a;
    }
    __syncthreads();

    for (int lv = 0; lv < 9; ++lv) {
        const int beg = c_LOFF[lv];
        const int cnt = c_LOFF[lv + 1] - beg;
        if (t < cnt * 12) {
            const int li = t / 12, e = t - li * 12;
            const int j = beg + li;
            const int r = e >> 2, cc = e & 3;
            if (lv == 0) {
                if (cc < 3) Rg[0][r * 3 + cc] = Rl[0][r * 3 + cc] * ((cc == 0) ? 1.f : -1.f);
                else        tg[0][r] = Jl[0][r];
            } else {
                const int p = c_PAR[j];
                if (cc < 3) {
                    Rg[j][r * 3 + cc] = Rg[p][r * 3 + 0] * Rl[j][0 + cc]
                                      + Rg[p][r * 3 + 1] * Rl[j][3 + cc]
                                      + Rg[p][r * 3 + 2] * Rl[j][6 + cc];
                } else {
                    const float t0 = Jl[j][0] - Jl[p][0];
                    const float t1 = Jl[j][1] - Jl[p][1];
                    const float t2 = Jl[j][2] - Jl[p][2];
                    tg[j][r] = Rg[p][r * 3 + 0] * t0 + Rg[p][r * 3 + 1] * t1
                             + Rg[p][r * 3 + 2] * t2 + tg[p][r];
                }
            }
        }
        __syncthreads();
    }

    if (t < 72) {
        const int i = t / 3, c = t - (t / 3) * 3;
        tA[i][c] = tg[i][c] - (Rg[i][c * 3 + 0] * Jl[i][0]
                             + Rg[i][c * 3 + 1] * Jl[i][1]
                             + Rg[i][c * 3 + 2] * Jl[i][2]);
    }
    __syncthreads();

    if (t < 218) xs_ws[(size_t)b * 218 + t] = xs[t];
    if (t < 216) Rg_ws[(size_t)b * 216 + t] = ((const float*)Rg)[t];
    if (t < 72)  tA_ws[(size_t)b * 72 + t]  = ((const float*)tA)[t];
}

// ---------------------------------------------------------------------------
// mgemm: Ml[b][0..1367] = sum_r xs[b][r] * CCX[r][0..1367].
// Grid 64 btiles(8 b) x 6 colgroups(228 cols) = 384 blocks.
// ---------------------------------------------------------------------------
__global__ __launch_bounds__(256) void mgemm(
    const float* __restrict__ xs_ws, const float* __restrict__ CCX,
    float* __restrict__ Ml)
{
    __shared__ float xsl[8 * 218];
    const int cg = blockIdx.x % 6;
    const int b0 = (blockIdx.x / 6) * 8;
    const int t = threadIdx.x;

    for (int i = t; i < 8 * 218; i += 256)
        xsl[i] = xs_ws[(size_t)b0 * 218 + i];    // fully coalesced
    __syncthreads();

    if (t < 228) {
        const int col = cg * 228 + t;
        float acc[8];
        #pragma unroll
        for (int bl = 0; bl < 8; ++bl) acc[bl] = 0.f;
        #pragma unroll 2
        for (int r = 0; r < 218; ++r) {
            const float cv = CCX[(size_t)r * RL + col];
            #pragma unroll
            for (int bl = 0; bl < 8; ++bl)
                acc[bl] += xsl[bl * 218 + r] * cv;   // LDS broadcast
        }
        #pragma unroll
        for (int bl = 0; bl < 8; ++bl)
            Ml[(size_t)(b0 + bl) * 1368 + col] = acc[bl];
    }
}

// ---------------------------------------------------------------------------
// joints: out[b][j][c] = sum_i Rg.Ml + tA*Wjr. One block per b, 256 threads
// (round-5 bug: 128 threads left Rgs[128..215] uninitialized).
// ---------------------------------------------------------------------------
__global__ __launch_bounds__(256) void joints_k(
    const float* __restrict__ Ml, const float* __restrict__ Rg_ws,
    const float* __restrict__ tA_ws, const float* __restrict__ CCX,
    float* __restrict__ out)
{
    __shared__ float Mls[1368];
    __shared__ float Wj[1368];
    __shared__ float Rgs[216];
    __shared__ float tAs[72];
    const int b = blockIdx.x;
    const int t = threadIdx.x;

    for (int i = t; i < 342; i += 256) {
        reinterpret_cast<float4*>(Mls)[i] =
            reinterpret_cast<const float4*>(Ml + (size_t)b * 1368)[i];
        reinterpret_cast<float4*>(Wj)[i] =
            reinterpret_cast<const float4*>(CCX + (size_t)218 * RL)[i];
    }
    if (t < 216) Rgs[t] = Rg_ws[(size_t)b * 216 + t];
    if (t < 72)  tAs[t] = tA_ws[(size_t)b * 72 + t];
    __syncthreads();

    if (t < 57) {
        const int j = t / 3, c = t - (t / 3) * 3;
        float a = 0.f;
        #pragma unroll
        for (int i = 0; i < 24; ++i) {
            const int mb = (j * 24 + i) * 3;
            a += Rgs[i * 9 + c * 3 + 0] * Mls[mb + 0]
               + Rgs[i * 9 + c * 3 + 1] * Mls[mb + 1]
               + Rgs[i * 9 + c * 3 + 2] * Mls[mb + 2]
               + tAs[i * 3 + c] * Wj[mb];
        }
        out[b * 57 + t] = a;
    }
}

extern "C" void kernel_launch(void* const* d_in, const int* in_sizes, int n_in,
                              void* d_out, int out_size, void* d_ws, size_t ws_size,
                              hipStream_t stream) {
    const float* beta  = (const float*)d_in[0];
    const float* theta = (const float*)d_in[1];
    const float* vt    = (const float*)d_in[2];
    const float* sd    = (const float*)d_in[3];
    const float* pd    = (const float*)d_in[4];
    const float* Jreg  = (const float*)d_in[5];
    const float* jr    = (const float*)d_in[6];
    const float* w     = (const float*)d_in[7];
    float* outp = (float*)d_out;

    // ws layout (floats): CCX | partials(region P) | Apack | Bpack.
    // xs/Rg/tA/Ml alias region P (partials dead after reduce_part).
    float* CCX = (float*)d_ws;
    float* partials = CCX + CCX_ELEMS;
    const size_t PARTN = (size_t)KSPLIT * MDIM * 512;
    unsigned short* Apack = (unsigned short*)(partials + PARTN);
    unsigned short* Bpack = Apack + (size_t)MT * KC * AIMG;

    float* xs_ws = partials;                    // 512*218
    float* Rg_ws = xs_ws + 512 * 218;           // 512*216
    float* tA_ws = Rg_ws + 512 * 216;           // 512*72
    float* Ml    = tA_ws + 512 * 72;            // 512*1368

    prep<<<920, 256, 0, stream>>>(vt, sd, pd, Jreg, jr, w, Apack, Bpack, CCX);
    gemm_mfma<<<MT * NT * KSPLIT, 256, 0, stream>>>(Apack, Bpack, partials);
    reduce_part<<<(MDIM * 128 + 255) / 256, 256, 0, stream>>>(partials, CCX);
    chain_k<<<512, 256, 0, stream>>>(beta, theta, CCX, xs_ws, Rg_ws, tA_ws);
    mgemm<<<384, 256, 0, stream>>>(xs_ws, CCX, Ml);
    joints_k<<<512, 256, 0, stream>>>(Ml, Rg_ws, tA_ws, CCX, outp);
}